// Round 2
// baseline (228.644 us; speedup 1.0000x reference)
//
#include <hip/hip_runtime.h>
#include <hip/hip_bf16.h>

// B=2, T=2048, C=1024, NH=16, HD=64. fp32 I/O, bf16/f16 MFMA internals.
#define B_   2
#define T_   2048
#define C_   1024
#define NH_  16
#define HD_  64

typedef __attribute__((ext_vector_type(8))) short short8;       // 8 bf16 (MFMA A/B frag, K=32)
typedef __attribute__((ext_vector_type(4))) float float4_;      // MFMA C/D frag
typedef __attribute__((ext_vector_type(4))) _Float16 half4_;    // f16 MFMA A/B frag, K=16
typedef __attribute__((ext_vector_type(2))) __fp16  fp16x2;     // cvt_pkrtz native type
typedef __attribute__((ext_vector_type(4))) unsigned short ushort4_;

static __device__ __forceinline__ unsigned short f2bf(float f) {
    union { float f; unsigned u; } v; v.f = f;
    unsigned r = v.u + 0x7fffu + ((v.u >> 16) & 1u);   // RNE
    return (unsigned short)(r >> 16);
}

// async global->LDS, 16B per lane: lane i lands at (wave-uniform base) + i*16B.
static __device__ __forceinline__ void g2l16(const void* g, void* l) {
    __builtin_amdgcn_global_load_lds(
        (const __attribute__((address_space(1))) void*)g,
        (__attribute__((address_space(3))) void*)l, 16, 0, 0);
}

// ---------------------------------------------------------------------------
// prep: one launch doing (1) x fp32->bf16 flat convert [blocks 0..2047],
// (2) w_attn transpose+convert [next 16*48], (3) w_proj transpose+convert
// [next 16*16]. All tiles 64x64, R=1024 rows for both weights.
// ---------------------------------------------------------------------------
__global__ __launch_bounds__(256) void prep(
    const float* __restrict__ x,      unsigned short* __restrict__ xb,
    const float* __restrict__ wA,     unsigned short* __restrict__ wTa,
    const float* __restrict__ wP,     unsigned short* __restrict__ wTp)
{
    const int t = threadIdx.x;
    int blk = blockIdx.x;
    if (blk < 2048) {                  // flat convert: 8 elems/thread
        int i = blk * 256 + t;
        const float4* p = (const float4*)x + (size_t)i * 2;
        float4 a = p[0], b = p[1];
        short8 o;
        o[0]=f2bf(a.x); o[1]=f2bf(a.y); o[2]=f2bf(a.z); o[3]=f2bf(a.w);
        o[4]=f2bf(b.x); o[5]=f2bf(b.y); o[6]=f2bf(b.z); o[7]=f2bf(b.w);
        *((short8*)xb + i) = o;
        return;
    }
    blk -= 2048;
    const float* in; unsigned short* out; int Cc;
    if (blk < 16 * 48) { in = wA; out = wTa; Cc = 3072; }
    else               { blk -= 16 * 48; in = wP; out = wTp; Cc = 1024; }
    const int r0 = (blk % 16) * 64, c0 = (blk / 16) * 64;
    const int R = 1024;
    __shared__ __align__(16) unsigned short Ts[64][72];
    #pragma unroll
    for (int cc = 0; cc < 2; ++cc) {
        int c = cc * 256 + t;
        int r = c >> 3, col = (c & 7) * 8;
        const float* p = in + (size_t)(r0 + r) * Cc + c0 + col;
        #pragma unroll
        for (int i = 0; i < 8; ++i) Ts[col + i][r] = f2bf(p[i]);
    }
    __syncthreads();
    #pragma unroll
    for (int cc = 0; cc < 2; ++cc) {
        int c = cc * 256 + t;
        int cr = c >> 3, oc = (c & 7) * 8;
        uint4 v = *(const uint4*)(&Ts[cr][oc]);
        *(uint4*)(out + (size_t)(c0 + cr) * R + r0 + oc) = v;
    }
}

// ---------------------------------------------------------------------------
// m97-structure GEMM: C[M,N] = A[M,K] @ Bt[N,K]^T, bf16 in, fp32 accum.
// BM x 128 tile, BK=32, 256 thr = 4 waves. BM=128: waves 2x2 (64x64 each).
// BM=64: waves 1x4 (64x32 each). WRITE_VT: v-part blocks (global col >=
// 2C) ALSO store f16 transposed V into vt[b*1024 + (col-2C)][token].
// ---------------------------------------------------------------------------
template <bool C_F32, int BM, bool WRITE_VT>
__global__ __launch_bounds__(256) void gemm_bt(
    const unsigned short* __restrict__ A,
    const unsigned short* __restrict__ Bt,
    void* __restrict__ Cv, unsigned short* __restrict__ vt,
    int M, int N, int K)
{
    __shared__ __align__(16) unsigned short As[BM * 32];
    __shared__ __align__(16) unsigned short Bs[128 * 32];
    const int t = threadIdx.x, lane = t & 63, w = t >> 6;
    const int quad = lane >> 4, ln = lane & 15;
    const int bm = blockIdx.x, bn = blockIdx.y;
    constexpr int NI = (BM == 128) ? 4 : 2;
    const int mw = (BM == 128) ? (w & 1) * 64 : 0;
    const int nw = (BM == 128) ? (w >> 1) * 64 : w * 32;
    float4_ acc[4][NI] = {};

    constexpr int AROWS = BM / 4;      // rows of A staged per wave
    const unsigned short* Ag = A  + (size_t)(bm * BM + w * AROWS + (lane >> 2)) * K + (lane & 3) * 8;
    const unsigned short* Bg = Bt + (size_t)(bn * 128 + w * 32 + (lane >> 2)) * K + (lane & 3) * 8;
    unsigned short* lA = &As[(w * AROWS) * 32 + lane * 8];
    unsigned short* lB = &Bs[(w * 32) * 32 + lane * 8];

    for (int k0 = 0; k0 < K; k0 += 32) {
        g2l16(Ag + k0, lA);
        if (BM == 128) g2l16(Ag + (size_t)16 * K + k0, lA + 16 * 32);
        g2l16(Bg + k0,                  lB);
        g2l16(Bg + (size_t)16 * K + k0, lB + 16 * 32);
        __syncthreads();
        short8 a[4], b[NI];
        #pragma unroll
        for (int i = 0; i < 4; ++i)
            a[i] = *(const short8*)(&As[(mw + i * 16 + ln) * 32 + quad * 8]);
        #pragma unroll
        for (int i = 0; i < NI; ++i)
            b[i] = *(const short8*)(&Bs[(nw + i * 16 + ln) * 32 + quad * 8]);
        #pragma unroll
        for (int mi = 0; mi < 4; ++mi)
            #pragma unroll
            for (int ni = 0; ni < NI; ++ni)
                acc[mi][ni] = __builtin_amdgcn_mfma_f32_16x16x32_bf16(
                    a[mi], b[ni], acc[mi][ni], 0, 0, 0);
        __syncthreads();
    }

    const int row0 = bm * BM + mw + quad * 4;
    const int col0 = bn * 128 + nw + ln;
    #pragma unroll
    for (int mi = 0; mi < 4; ++mi)
        #pragma unroll
        for (int ni = 0; ni < NI; ++ni) {
            #pragma unroll
            for (int i = 0; i < 4; ++i) {
                size_t idx = (size_t)(row0 + mi * 16 + i) * N + col0 + ni * 16;
                if (C_F32) ((float*)Cv)[idx] = acc[mi][ni][i];
                else       ((unsigned short*)Cv)[idx] = f2bf(acc[mi][ni][i]);
            }
            if (WRITE_VT && col0 + ni * 16 >= 2 * C_) {
                int d     = col0 + ni * 16 - 2 * C_;       // 0..1023
                int token = row0 + mi * 16;                // 4-aligned, +i
                int b     = token >> 11, tloc = token & 2047;
                union { fp16x2 h2[2]; ushort4_ u4; } pk;
                pk.h2[0] = __builtin_amdgcn_cvt_pkrtz(acc[mi][ni][0], acc[mi][ni][1]);
                pk.h2[1] = __builtin_amdgcn_cvt_pkrtz(acc[mi][ni][2], acc[mi][ni][3]);
                *(ushort4_*)(vt + ((size_t)b * 1024 + d) * T_ + tloc) = pk.u4;
            }
        }
}

// ---------------------------------------------------------------------------
// Flash attention, 512 thr = 8 waves. 128-row Q-tile. kt-PARITY SPLIT:
// wave w: qg = w&3 owns q-rows qg*32..+31 (qm pair), kp = w>>2 selects
// even/odd 64-token K-tile. Per barrier interval TWO K-tiles are staged
// (double-buffered by parity) and each wave computes one -> 16 waves/CU
// (4/SIMD), same LDS-frag traffic per K-tile, half the barriers.
// Fixed-shift softmax (no running max) => parity partials are pure sums,
// combined via LDS at the end.
// __launch_bounds__(512, 2): 2nd arg is MIN BLOCKS PER CU (CUDA semantics,
// round-1 evidence: (512,4) forced VGPR=64 -> scratch spill, WRITE_SIZE
// 8->20MB). (512,2) -> 16 waves/CU -> 128-VGPR cap, state (~100) fits.
//   St[kk][q] = mfma_16x16x32_bf16(A=K_frag, B=Q_frag)
//   P = exp2(St*C1 - C2) in-register; C-layout == B-operand layout of the
//   K=16 f16 MFMA: Ot[d][q] += mfma_16x16x16f16(A=Vt_frag, B=P_frag).
// Vs bank-conflict fix: byte-addr ^= (row&8) (8B half-swap inside each
// aligned 16B block; write-side = register swap, read-side = addr XOR).
// ---------------------------------------------------------------------------
__global__ __launch_bounds__(512, 2) void attn(
    const unsigned short* __restrict__ qkv,
    const unsigned short* __restrict__ vt,
    unsigned short* __restrict__ Y)
{
    // Qs 128x72 (18432B) | Ks [2][64][72] (18432B) | Vs [2][64][72] (18432B)
    __shared__ __align__(16) char smem_[55296];
    auto Qs = (unsigned short (*)[72])(smem_);
    auto Ks = (unsigned short (*)[64][72])(smem_ + 18432);
    auto Vs = (unsigned short (*)[64][72])(smem_ + 36864);

    const int t = threadIdx.x;
    const int qt = blockIdx.x, bh = blockIdx.y;
    const int b = bh >> 4, h = bh & 15;
    const int lane = t & 63, w = t >> 6;
    const int quad = lane >> 4, ln = lane & 15;
    const int qg = w & 3, kp = w >> 2;

    const unsigned short* Qg  = qkv + (size_t)b * T_ * (3 * C_) + (size_t)h * HD_;
    const unsigned short* Kg  = Qg + C_;
    const unsigned short* Vtg = vt + (size_t)bh * HD_ * T_;

    // stage Q tile (128x64): 1024 16B chunks, 2/thread
    #pragma unroll
    for (int cc = 0; cc < 2; ++cc) {
        int c = cc * 512 + t;
        int r = c >> 3, col = (c & 7) * 8;
        *(uint4*)(&Qs[r][col]) = *(const uint4*)(Qg + (size_t)(qt * 128 + r) * (3 * C_) + col);
    }

    // K/V staging coords: thread t -> row t>>3 (0..63), col (t&7)*8
    const int r0 = t >> 3, c0v = (t & 7) * 8;
    const int vsw = r0 & 8;            // write-side half-swap flag

    // prefetch it=0 (both parities)
    uint4 kr[2], vr[2];
    #pragma unroll
    for (int p = 0; p < 2; ++p) {
        kr[p] = *(const uint4*)(Kg + (size_t)(p * 64 + r0) * (3 * C_) + c0v);
        vr[p] = *(const uint4*)(Vtg + (size_t)r0 * T_ + p * 64 + c0v);
    }

    __syncthreads();

    // hoisted Q frags: B-operand, lane holds Q[q=qg*32+qm*16+ln][d=dh*32+quad*8..+7]
    short8 qf[2][2];
    #pragma unroll
    for (int qm = 0; qm < 2; ++qm)
        #pragma unroll
        for (int dh = 0; dh < 2; ++dh)
            qf[qm][dh] = *(const short8*)(&Qs[qg * 32 + qm * 16 + ln][dh * 32 + quad * 8]);

    float4_ ot[4][2] = {};             // [dt][qm]: Ot[d=dt*16+quad*4+i][q=qm*16+ln]
    float ls[2] = {0.f, 0.f};
    const float C1 = 0.125f * 1.44269504f;   // scale * log2(e)
    const float C2 = 8.0f * 1.44269504f;     // fixed shift * log2(e)

    for (int it = 0; it < T_ / 128; ++it) {
        if (it) __syncthreads();       // prior iter's frag reads complete
        #pragma unroll
        for (int p = 0; p < 2; ++p) {
            *(uint4*)(&Ks[p][r0][c0v]) = kr[p];
            uint4 v = vr[p];
            if (vsw) { uint4 s; s.x = v.z; s.y = v.w; s.z = v.x; s.w = v.y; v = s; }
            *(uint4*)(&Vs[p][r0][c0v]) = v;
        }
        __syncthreads();

        // next iter's global loads in flight across this iter's compute
        if (it + 1 < T_ / 128) {
            int kb = (it + 1) * 128;
            #pragma unroll
            for (int p = 0; p < 2; ++p) {
                kr[p] = *(const uint4*)(Kg + (size_t)(kb + p * 64 + r0) * (3 * C_) + c0v);
                vr[p] = *(const uint4*)(Vtg + (size_t)r0 * T_ + kb + p * 64 + c0v);
            }
        }

        // QK^T + softmax numerator on this wave's parity tile
        half4_ pf[4][2];
        #pragma unroll
        for (int ct = 0; ct < 4; ++ct) {
            short8 kb0 = *(const short8*)(&Ks[kp][ct * 16 + ln][quad * 8]);
            short8 kb1 = *(const short8*)(&Ks[kp][ct * 16 + ln][32 + quad * 8]);
            #pragma unroll
            for (int qm = 0; qm < 2; ++qm) {
                float4_ st = {};
                st = __builtin_amdgcn_mfma_f32_16x16x32_bf16(kb0, qf[qm][0], st, 0, 0, 0);
                st = __builtin_amdgcn_mfma_f32_16x16x32_bf16(kb1, qf[qm][1], st, 0, 0, 0);
                float p0 = __builtin_amdgcn_exp2f(st[0] * C1 - C2);
                float p1 = __builtin_amdgcn_exp2f(st[1] * C1 - C2);
                float p2 = __builtin_amdgcn_exp2f(st[2] * C1 - C2);
                float p3 = __builtin_amdgcn_exp2f(st[3] * C1 - C2);
                ls[qm] += (p0 + p1) + (p2 + p3);
                union { fp16x2 h2[2]; half4_ h4; } u;
                u.h2[0] = __builtin_amdgcn_cvt_pkrtz(p0, p1);
                u.h2[1] = __builtin_amdgcn_cvt_pkrtz(p2, p3);
                pf[ct][qm] = u.h4;
            }
        }

        // Ot += V^T P^T : A-frag = Vs[d=dt*16+ln][kk=ct*16+quad*4 ..+3]
        const char* vbase = (const char*)(&Vs[kp][0][0]);
        const int rsw = ln & 8;        // read-side addr XOR
        #pragma unroll
        for (int dt = 0; dt < 4; ++dt) {
            int roff = (dt * 16 + ln) * 144;
            #pragma unroll
            for (int ct = 0; ct < 4; ++ct) {
                half4_ va = *(const half4_*)(vbase + roff + ((ct * 32 + quad * 8) ^ rsw));
                #pragma unroll
                for (int qm = 0; qm < 2; ++qm)
                    ot[dt][qm] = __builtin_amdgcn_mfma_f32_16x16x16f16(
                        va, pf[ct][qm], ot[dt][qm], 0, 0, 0);
            }
        }
    }

    // combine parity partials through LDS (overlays Qs/Ks region)
    __syncthreads();
    auto part = (float (*)[64][34])(smem_);          // [qg][lane][32 pad 34]
    auto lsp  = (float (*)[64][2])(smem_ + 34816);
    if (w >= 4) {
        float* pp = &part[qg][lane][0];
        #pragma unroll
        for (int dt = 0; dt < 4; ++dt)
            #pragma unroll
            for (int qm = 0; qm < 2; ++qm)
                #pragma unroll
                for (int i = 0; i < 4; ++i)
                    pp[dt * 8 + qm * 4 + i] = ot[dt][qm][i];
        lsp[qg][lane][0] = ls[0];
        lsp[qg][lane][1] = ls[1];
    }
    __syncthreads();
    if (w < 4) {
        const float* pp = &part[qg][lane][0];
        #pragma unroll
        for (int dt = 0; dt < 4; ++dt)
            #pragma unroll
            for (int qm = 0; qm < 2; ++qm)
                #pragma unroll
                for (int i = 0; i < 4; ++i)
                    ot[dt][qm][i] += pp[dt * 8 + qm * 4 + i];
        ls[0] += lsp[qg][lane][0];
        ls[1] += lsp[qg][lane][1];

        // reduce ls across the 4 quads (lane bits 4,5)
        #pragma unroll
        for (int qm = 0; qm < 2; ++qm) {
            ls[qm] += __shfl_xor(ls[qm], 16, 64);
            ls[qm] += __shfl_xor(ls[qm], 32, 64);
        }

        // epilogue: Y[b, q, h*64 + d]; q = qt*128 + qg*32 + qm*16 + ln
        #pragma unroll
        for (int qm = 0; qm < 2; ++qm) {
            unsigned short* Yr = Y + ((size_t)b * T_ + qt * 128 + qg * 32 + qm * 16 + ln) * C_ + h * HD_;
            float inv = 1.0f / ls[qm];
            #pragma unroll
            for (int dt = 0; dt < 4; ++dt)
                #pragma unroll
                for (int i = 0; i < 4; ++i)
                    Yr[dt * 16 + quad * 4 + i] = f2bf(ot[dt][qm][i] * inv);
        }
    }
}

extern "C" void kernel_launch(void* const* d_in, const int* in_sizes, int n_in,
                              void* d_out, int out_size, void* d_ws, size_t ws_size,
                              hipStream_t stream)
{
    const float* x      = (const float*)d_in[0];   // [4096,1024]
    const float* w_attn = (const float*)d_in[1];   // [1024,3072]
    const float* w_proj = (const float*)d_in[2];   // [1024,1024]
    float* out = (float*)d_out;                    // [4096,1024]

    // ws (2B elems): qkv 12.58M | y/xb 4.19M | wTa 3.15M | wTp 1.05M | vt 4.19M
    unsigned short* qkv = (unsigned short*)d_ws;
    unsigned short* y   = qkv + (size_t)4096 * 3072;   // also xb (dead after gemm1)
    unsigned short* wTa = y   + (size_t)4096 * 1024;
    unsigned short* wTp = wTa + (size_t)3072 * 1024;
    unsigned short* vt  = wTp + (size_t)1024 * 1024;   // f16
    unsigned short* xb  = y;

    prep<<<2048 + 16 * 48 + 16 * 16, 256, 0, stream>>>(x, xb, w_attn, wTa, w_proj, wTp);

    gemm_bt<false, 128, true><<<dim3(32, 24), 256, 0, stream>>>(
        xb, wTa, qkv, vt, 4096, 3072, 1024);
    attn<<<dim3(16, 32), 512, 0, stream>>>(qkv, vt, y);
    gemm_bt<true, 64, false><<<dim3(64, 8), 256, 0, stream>>>(
        y, wTp, out, nullptr, 4096, 1024, 1024);
}

// Round 3
// 206.171 us; speedup vs baseline: 1.1090x; 1.1090x over previous
//
#include <hip/hip_runtime.h>
#include <hip/hip_bf16.h>

// B=2, T=2048, C=1024, NH=16, HD=64. fp32 I/O, bf16/f16 MFMA internals.
#define B_   2
#define T_   2048
#define C_   1024
#define NH_  16
#define HD_  64

typedef __attribute__((ext_vector_type(8))) short short8;       // 8 bf16 (MFMA A/B frag, K=32)
typedef __attribute__((ext_vector_type(4))) float float4_;      // MFMA C/D frag
typedef __attribute__((ext_vector_type(4))) _Float16 half4_;    // f16 MFMA A/B frag, K=16
typedef __attribute__((ext_vector_type(2))) __fp16  fp16x2;     // cvt_pkrtz native type
typedef __attribute__((ext_vector_type(4))) unsigned short ushort4_;

static __device__ __forceinline__ unsigned short f2bf(float f) {
    union { float f; unsigned u; } v; v.f = f;
    unsigned r = v.u + 0x7fffu + ((v.u >> 16) & 1u);   // RNE
    return (unsigned short)(r >> 16);
}

// async global->LDS, 16B per lane: lane i lands at (wave-uniform base) + i*16B.
static __device__ __forceinline__ void g2l16(const void* g, void* l) {
    __builtin_amdgcn_global_load_lds(
        (const __attribute__((address_space(1))) void*)g,
        (__attribute__((address_space(3))) void*)l, 16, 0, 0);
}

// ---------------------------------------------------------------------------
// prep: one launch doing (1) x fp32->bf16 flat convert [blocks 0..2047],
// (2) w_attn transpose+convert [next 16*48], (3) w_proj transpose+convert
// [next 16*16]. All tiles 64x64, R=1024 rows for both weights.
// ---------------------------------------------------------------------------
__global__ __launch_bounds__(256) void prep(
    const float* __restrict__ x,      unsigned short* __restrict__ xb,
    const float* __restrict__ wA,     unsigned short* __restrict__ wTa,
    const float* __restrict__ wP,     unsigned short* __restrict__ wTp)
{
    const int t = threadIdx.x;
    int blk = blockIdx.x;
    if (blk < 2048) {                  // flat convert: 8 elems/thread
        int i = blk * 256 + t;
        const float4* p = (const float4*)x + (size_t)i * 2;
        float4 a = p[0], b = p[1];
        short8 o;
        o[0]=f2bf(a.x); o[1]=f2bf(a.y); o[2]=f2bf(a.z); o[3]=f2bf(a.w);
        o[4]=f2bf(b.x); o[5]=f2bf(b.y); o[6]=f2bf(b.z); o[7]=f2bf(b.w);
        *((short8*)xb + i) = o;
        return;
    }
    blk -= 2048;
    const float* in; unsigned short* out; int Cc;
    if (blk < 16 * 48) { in = wA; out = wTa; Cc = 3072; }
    else               { blk -= 16 * 48; in = wP; out = wTp; Cc = 1024; }
    const int r0 = (blk % 16) * 64, c0 = (blk / 16) * 64;
    const int R = 1024;
    __shared__ __align__(16) unsigned short Ts[64][72];
    #pragma unroll
    for (int cc = 0; cc < 2; ++cc) {
        int c = cc * 256 + t;
        int r = c >> 3, col = (c & 7) * 8;
        const float* p = in + (size_t)(r0 + r) * Cc + c0 + col;
        #pragma unroll
        for (int i = 0; i < 8; ++i) Ts[col + i][r] = f2bf(p[i]);
    }
    __syncthreads();
    #pragma unroll
    for (int cc = 0; cc < 2; ++cc) {
        int c = cc * 256 + t;
        int cr = c >> 3, oc = (c & 7) * 8;
        uint4 v = *(const uint4*)(&Ts[cr][oc]);
        *(uint4*)(out + (size_t)(c0 + cr) * R + r0 + oc) = v;
    }
}

// ---------------------------------------------------------------------------
// m97-structure GEMM: C[M,N] = A[M,K] @ Bt[N,K]^T, bf16 in, fp32 accum.
// BM x 128 tile, BK=32, 256 thr = 4 waves. BM=128: waves 2x2 (64x64 each).
// BM=64: waves 1x4 (64x32 each). WRITE_VT: v-part blocks (global col >=
// 2C) ALSO store f16 transposed V into vt[b*1024 + (col-2C)][token].
// T1 XCD swizzle: nwg%8==0 for both launches (768, 512) -> simple chunked
// bijection; each XCD gets a contiguous run of output tiles (gemm2: one
// full bn stripe per XCD) so shared B-panels stay in ONE L2.
// ---------------------------------------------------------------------------
template <bool C_F32, int BM, bool WRITE_VT>
__global__ __launch_bounds__(256) void gemm_bt(
    const unsigned short* __restrict__ A,
    const unsigned short* __restrict__ Bt,
    void* __restrict__ Cv, unsigned short* __restrict__ vt,
    int M, int N, int K)
{
    __shared__ __align__(16) unsigned short As[BM * 32];
    __shared__ __align__(16) unsigned short Bs[128 * 32];
    const int t = threadIdx.x, lane = t & 63, w = t >> 6;
    const int quad = lane >> 4, ln = lane & 15;

    // XCD-aware bijective swizzle (requires nwg % 8 == 0; holds: 768, 512)
    const int nwg  = gridDim.x * gridDim.y;
    const int flat = blockIdx.y * gridDim.x + blockIdx.x;
    const int q8   = nwg >> 3;
    const int swz  = (flat & 7) * q8 + (flat >> 3);
    const int bm = swz % gridDim.x, bn = swz / gridDim.x;

    constexpr int NI = (BM == 128) ? 4 : 2;
    const int mw = (BM == 128) ? (w & 1) * 64 : 0;
    const int nw = (BM == 128) ? (w >> 1) * 64 : w * 32;
    float4_ acc[4][NI] = {};

    constexpr int AROWS = BM / 4;      // rows of A staged per wave
    const unsigned short* Ag = A  + (size_t)(bm * BM + w * AROWS + (lane >> 2)) * K + (lane & 3) * 8;
    const unsigned short* Bg = Bt + (size_t)(bn * 128 + w * 32 + (lane >> 2)) * K + (lane & 3) * 8;
    unsigned short* lA = &As[(w * AROWS) * 32 + lane * 8];
    unsigned short* lB = &Bs[(w * 32) * 32 + lane * 8];

    for (int k0 = 0; k0 < K; k0 += 32) {
        g2l16(Ag + k0, lA);
        if (BM == 128) g2l16(Ag + (size_t)16 * K + k0, lA + 16 * 32);
        g2l16(Bg + k0,                  lB);
        g2l16(Bg + (size_t)16 * K + k0, lB + 16 * 32);
        __syncthreads();
        short8 a[4], b[NI];
        #pragma unroll
        for (int i = 0; i < 4; ++i)
            a[i] = *(const short8*)(&As[(mw + i * 16 + ln) * 32 + quad * 8]);
        #pragma unroll
        for (int i = 0; i < NI; ++i)
            b[i] = *(const short8*)(&Bs[(nw + i * 16 + ln) * 32 + quad * 8]);
        #pragma unroll
        for (int mi = 0; mi < 4; ++mi)
            #pragma unroll
            for (int ni = 0; ni < NI; ++ni)
                acc[mi][ni] = __builtin_amdgcn_mfma_f32_16x16x32_bf16(
                    a[mi], b[ni], acc[mi][ni], 0, 0, 0);
        __syncthreads();
    }

    const int row0 = bm * BM + mw + quad * 4;
    const int col0 = bn * 128 + nw + ln;
    #pragma unroll
    for (int mi = 0; mi < 4; ++mi)
        #pragma unroll
        for (int ni = 0; ni < NI; ++ni) {
            #pragma unroll
            for (int i = 0; i < 4; ++i) {
                size_t idx = (size_t)(row0 + mi * 16 + i) * N + col0 + ni * 16;
                if (C_F32) ((float*)Cv)[idx] = acc[mi][ni][i];
                else       ((unsigned short*)Cv)[idx] = f2bf(acc[mi][ni][i]);
            }
            if (WRITE_VT && col0 + ni * 16 >= 2 * C_) {
                int d     = col0 + ni * 16 - 2 * C_;       // 0..1023
                int token = row0 + mi * 16;                // 4-aligned, +i
                int b     = token >> 11, tloc = token & 2047;
                union { fp16x2 h2[2]; ushort4_ u4; } pk;
                pk.h2[0] = __builtin_amdgcn_cvt_pkrtz(acc[mi][ni][0], acc[mi][ni][1]);
                pk.h2[1] = __builtin_amdgcn_cvt_pkrtz(acc[mi][ni][2], acc[mi][ni][3]);
                *(ushort4_*)(vt + ((size_t)b * 1024 + d) * T_ + tloc) = pk.u4;
            }
        }
}

// ---------------------------------------------------------------------------
// Flash attention, W=32: 256 threads = 4 waves, 128-row Q-tile, wave w owns
// q-rows w*32..+31 as 2 subtiles (qm). KT=64. Each Ks/Vs LDS fragment read
// feeds 2 MFMAs (the qm pair). (Round-0 structure — the 8-wave parity
// variants of R1/R2 regressed 70->86/94 us; reverted.)
//   St[kk][q] = mfma_16x16x32_bf16(A=K_frag, B=Q_frag)  -> C-layout
//   P = exp2(St*C1 - C2) in-register (C1=scale*log2e, C2=8*log2e; fixed
//   shift cancels in the final divide). C-layout == B-operand layout of the
//   K=16 f16 MFMA, so PV needs NO LDS round-trip:
//   Ot[d][q] += mfma_16x16x16f16(A=Vt_frag, B=P_frag).
// K/V register-prefetched one iter ahead (4 uint4 = 16 VGPRs).
// Vs bank-conflict swizzle (verified R1/R2: conflicts 6.3M->3.7M):
// byte-addr ^= (row&8) = 8B half-swap inside each aligned 16B block.
// Write-side: register swap of the uint4 halves; read-side: addr XOR ln&8.
// Removes the ln/ln+8 2-way alias on the 8B PV reads.
// ---------------------------------------------------------------------------
__global__ __launch_bounds__(256) void attn(
    const unsigned short* __restrict__ qkv,
    const unsigned short* __restrict__ vt,
    unsigned short* __restrict__ Y)
{
    __shared__ __align__(16) unsigned short Qs[128][72];  // bf16 [q][d]
    __shared__ __align__(16) unsigned short Ks[64][72];   // bf16 [kk][d]
    __shared__ __align__(16) unsigned short Vs[64][72];   // f16  [d][kk], swizzled

    const int t = threadIdx.x;
    const int qt = blockIdx.x, bh = blockIdx.y;
    const int b = bh >> 4, h = bh & 15;
    const int lane = t & 63, w = t >> 6;
    const int quad = lane >> 4, ln = lane & 15;

    const unsigned short* Qg  = qkv + (size_t)b * T_ * (3 * C_) + (size_t)h * HD_;
    const unsigned short* Kg  = Qg + C_;
    const unsigned short* Vtg = vt + (size_t)bh * HD_ * T_;

    // stage Q tile (128x64): 1024 chunks, 4/thread
    #pragma unroll
    for (int cc = 0; cc < 4; ++cc) {
        int c = cc * 256 + t;
        int r = c >> 3, col = (c & 7) * 8;
        *(uint4*)(&Qs[r][col]) = *(const uint4*)(Qg + (size_t)(qt * 128 + r) * (3 * C_) + col);
    }

    // K/V staging coords: chunk c = cc*256+t -> row cc*32+(t>>3), col (t&7)*8
    const int r0 = t >> 3, c0v = (t & 7) * 8;
    const int r1 = r0 + 32;
    const int vsw = r0 & 8;            // write-side half-swap flag (r1&8 == r0&8)

    // prefetch kt=0
    uint4 kr0 = *(const uint4*)(Kg + (size_t)r0 * (3 * C_) + c0v);
    uint4 kr1 = *(const uint4*)(Kg + (size_t)r1 * (3 * C_) + c0v);
    uint4 vr0 = *(const uint4*)(Vtg + (size_t)r0 * T_ + c0v);
    uint4 vr1 = *(const uint4*)(Vtg + (size_t)r1 * T_ + c0v);

    __syncthreads();

    // hoisted Q frags: B-operand, lane holds Q[q=w*32+qm*16+ln][d=dh*32+quad*8..+7]
    short8 qf[2][2];
    #pragma unroll
    for (int qm = 0; qm < 2; ++qm)
        #pragma unroll
        for (int dh = 0; dh < 2; ++dh)
            qf[qm][dh] = *(const short8*)(&Qs[w * 32 + qm * 16 + ln][dh * 32 + quad * 8]);

    float4_ ot[4][2] = {};             // [dt][qm]: Ot[d=dt*16+quad*4+i][q=qm*16+ln]
    float ls[2] = {0.f, 0.f};
    const float C1 = 0.125f * 1.44269504f;   // scale * log2(e)
    const float C2 = 8.0f * 1.44269504f;     // fixed shift * log2(e)

    for (int kt = 0; kt < T_ / 64; ++kt) {
        if (kt) __syncthreads();       // prior iter's frag reads complete
        *(uint4*)(&Ks[r0][c0v]) = kr0;
        *(uint4*)(&Ks[r1][c0v]) = kr1;
        {
            uint4 v0 = vr0, v1 = vr1;
            if (vsw) {
                uint4 s;
                s.x = v0.z; s.y = v0.w; s.z = v0.x; s.w = v0.y; v0 = s;
                s.x = v1.z; s.y = v1.w; s.z = v1.x; s.w = v1.y; v1 = s;
            }
            *(uint4*)(&Vs[r0][c0v]) = v0;
            *(uint4*)(&Vs[r1][c0v]) = v1;
        }
        __syncthreads();

        // next iter's global loads in flight across this iter's compute
        if (kt + 1 < T_ / 64) {
            int kb = (kt + 1) * 64;
            kr0 = *(const uint4*)(Kg + (size_t)(kb + r0) * (3 * C_) + c0v);
            kr1 = *(const uint4*)(Kg + (size_t)(kb + r1) * (3 * C_) + c0v);
            vr0 = *(const uint4*)(Vtg + (size_t)r0 * T_ + kb + c0v);
            vr1 = *(const uint4*)(Vtg + (size_t)r1 * T_ + kb + c0v);
        }

        // QK^T + softmax numerator, per ct-tile (kk = ct*16+quad*4+reg)
        half4_ pf[4][2];
        #pragma unroll
        for (int ct = 0; ct < 4; ++ct) {
            short8 kb0 = *(const short8*)(&Ks[ct * 16 + ln][quad * 8]);
            short8 kb1 = *(const short8*)(&Ks[ct * 16 + ln][32 + quad * 8]);
            #pragma unroll
            for (int qm = 0; qm < 2; ++qm) {
                float4_ st = {};
                st = __builtin_amdgcn_mfma_f32_16x16x32_bf16(kb0, qf[qm][0], st, 0, 0, 0);
                st = __builtin_amdgcn_mfma_f32_16x16x32_bf16(kb1, qf[qm][1], st, 0, 0, 0);
                float p0 = __builtin_amdgcn_exp2f(st[0] * C1 - C2);
                float p1 = __builtin_amdgcn_exp2f(st[1] * C1 - C2);
                float p2 = __builtin_amdgcn_exp2f(st[2] * C1 - C2);
                float p3 = __builtin_amdgcn_exp2f(st[3] * C1 - C2);
                ls[qm] += (p0 + p1) + (p2 + p3);
                union { fp16x2 h2[2]; half4_ h4; } u;
                u.h2[0] = __builtin_amdgcn_cvt_pkrtz(p0, p1);
                u.h2[1] = __builtin_amdgcn_cvt_pkrtz(p2, p3);
                pf[ct][qm] = u.h4;
            }
        }

        // Ot += V^T P^T : A-frag = Vs[d=dt*16+ln][kk=ct*16+quad*4 ..+3]
        const char* vbase = (const char*)(&Vs[0][0]);
        const int rsw = ln & 8;        // read-side addr XOR (row&8 == ln&8)
        #pragma unroll
        for (int dt = 0; dt < 4; ++dt) {
            int roff = (dt * 16 + ln) * 144;
            #pragma unroll
            for (int ct = 0; ct < 4; ++ct) {
                half4_ va = *(const half4_*)(vbase + roff + ((ct * 32 + quad * 8) ^ rsw));
                #pragma unroll
                for (int qm = 0; qm < 2; ++qm)
                    ot[dt][qm] = __builtin_amdgcn_mfma_f32_16x16x16f16(
                        va, pf[ct][qm], ot[dt][qm], 0, 0, 0);
            }
        }
    }

    // reduce ls across the 4 quads (lane bits 4,5)
    #pragma unroll
    for (int qm = 0; qm < 2; ++qm) {
        ls[qm] += __shfl_xor(ls[qm], 16, 64);
        ls[qm] += __shfl_xor(ls[qm], 32, 64);
    }

    // epilogue: Y[b, q, h*64 + d]; q = qt*128 + w*32 + qm*16 + ln
    #pragma unroll
    for (int qm = 0; qm < 2; ++qm) {
        unsigned short* Yr = Y + ((size_t)b * T_ + qt * 128 + w * 32 + qm * 16 + ln) * C_ + h * HD_;
        float inv = 1.0f / ls[qm];
        #pragma unroll
        for (int dt = 0; dt < 4; ++dt)
            #pragma unroll
            for (int i = 0; i < 4; ++i)
                Yr[dt * 16 + quad * 4 + i] = f2bf(ot[dt][qm][i] * inv);
    }
}

extern "C" void kernel_launch(void* const* d_in, const int* in_sizes, int n_in,
                              void* d_out, int out_size, void* d_ws, size_t ws_size,
                              hipStream_t stream)
{
    const float* x      = (const float*)d_in[0];   // [4096,1024]
    const float* w_attn = (const float*)d_in[1];   // [1024,3072]
    const float* w_proj = (const float*)d_in[2];   // [1024,1024]
    float* out = (float*)d_out;                    // [4096,1024]

    // ws (2B elems): qkv 12.58M | y/xb 4.19M | wTa 3.15M | wTp 1.05M | vt 4.19M
    unsigned short* qkv = (unsigned short*)d_ws;
    unsigned short* y   = qkv + (size_t)4096 * 3072;   // also xb (dead after gemm1)
    unsigned short* wTa = y   + (size_t)4096 * 1024;
    unsigned short* wTp = wTa + (size_t)3072 * 1024;
    unsigned short* vt  = wTp + (size_t)1024 * 1024;   // f16
    unsigned short* xb  = y;

    prep<<<2048 + 16 * 48 + 16 * 16, 256, 0, stream>>>(x, xb, w_attn, wTa, w_proj, wTp);

    gemm_bt<false, 128, true><<<dim3(32, 24), 256, 0, stream>>>(
        xb, wTa, qkv, vt, 4096, 3072, 1024);
    attn<<<dim3(16, 32), 256, 0, stream>>>(qkv, vt, y);
    gemm_bt<true, 64, false><<<dim3(64, 8), 256, 0, stream>>>(
        y, wTp, out, nullptr, 4096, 1024, 1024);
}

// Round 4
// 189.997 us; speedup vs baseline: 1.2034x; 1.0851x over previous
//
#include <hip/hip_runtime.h>
#include <hip/hip_bf16.h>

// B=2, T=2048, C=1024, NH=16, HD=64. fp32 I/O, bf16/f16 MFMA internals.
#define B_   2
#define T_   2048
#define C_   1024
#define NH_  16
#define HD_  64

typedef __attribute__((ext_vector_type(8))) short short8;       // 8 bf16 (MFMA A/B frag, K=32)
typedef __attribute__((ext_vector_type(4))) float float4_;      // MFMA C/D frag
typedef __attribute__((ext_vector_type(4))) _Float16 half4_;    // f16 MFMA A/B frag, K=16
typedef __attribute__((ext_vector_type(2))) __fp16  fp16x2;     // cvt_pkrtz native type
typedef __attribute__((ext_vector_type(4))) unsigned short ushort4_;

static __device__ __forceinline__ unsigned short f2bf(float f) {
    union { float f; unsigned u; } v; v.f = f;
    unsigned r = v.u + 0x7fffu + ((v.u >> 16) & 1u);   // RNE
    return (unsigned short)(r >> 16);
}

// async global->LDS, 16B per lane: lane i lands at (wave-uniform base) + i*16B.
static __device__ __forceinline__ void g2l16(const void* g, void* l) {
    __builtin_amdgcn_global_load_lds(
        (const __attribute__((address_space(1))) void*)g,
        (__attribute__((address_space(3))) void*)l, 16, 0, 0);
}

// ---------------------------------------------------------------------------
// prep: one launch doing (1) x fp32->bf16 flat convert [blocks 0..2047],
// (2) w_attn transpose+convert [next 16*48], (3) w_proj transpose+convert
// [next 16*16]. All tiles 64x64, R=1024 rows for both weights.
// ---------------------------------------------------------------------------
__global__ __launch_bounds__(256) void prep(
    const float* __restrict__ x,      unsigned short* __restrict__ xb,
    const float* __restrict__ wA,     unsigned short* __restrict__ wTa,
    const float* __restrict__ wP,     unsigned short* __restrict__ wTp)
{
    const int t = threadIdx.x;
    int blk = blockIdx.x;
    if (blk < 2048) {                  // flat convert: 8 elems/thread
        int i = blk * 256 + t;
        const float4* p = (const float4*)x + (size_t)i * 2;
        float4 a = p[0], b = p[1];
        short8 o;
        o[0]=f2bf(a.x); o[1]=f2bf(a.y); o[2]=f2bf(a.z); o[3]=f2bf(a.w);
        o[4]=f2bf(b.x); o[5]=f2bf(b.y); o[6]=f2bf(b.z); o[7]=f2bf(b.w);
        *((short8*)xb + i) = o;
        return;
    }
    blk -= 2048;
    const float* in; unsigned short* out; int Cc;
    if (blk < 16 * 48) { in = wA; out = wTa; Cc = 3072; }
    else               { blk -= 16 * 48; in = wP; out = wTp; Cc = 1024; }
    const int r0 = (blk % 16) * 64, c0 = (blk / 16) * 64;
    const int R = 1024;
    __shared__ __align__(16) unsigned short Ts[64][72];
    #pragma unroll
    for (int cc = 0; cc < 2; ++cc) {
        int c = cc * 256 + t;
        int r = c >> 3, col = (c & 7) * 8;
        const float* p = in + (size_t)(r0 + r) * Cc + c0 + col;
        #pragma unroll
        for (int i = 0; i < 8; ++i) Ts[col + i][r] = f2bf(p[i]);
    }
    __syncthreads();
    #pragma unroll
    for (int cc = 0; cc < 2; ++cc) {
        int c = cc * 256 + t;
        int cr = c >> 3, oc = (c & 7) * 8;
        uint4 v = *(const uint4*)(&Ts[cr][oc]);
        *(uint4*)(out + (size_t)(c0 + cr) * R + r0 + oc) = v;
    }
}

// ---------------------------------------------------------------------------
// m97-structure GEMM: C[M,N] = A[M,K] @ Bt[N,K]^T, bf16 in, fp32 accum.
// BM x 128 tile, BK=32, 256 thr = 4 waves. BM=128: waves 2x2 (64x64 each).
// BM=64: waves 1x4 (64x32 each). WRITE_VT: v-part blocks (global col >=
// 2C) ALSO store f16 transposed V into vt[b*1024 + (col-2C)][token].
// (R3 tried T1 XCD block-swizzle: regressed ~9us — inputs are L3-resident,
// consistent with m160's "-2% when L3-fit". Reverted to natural order.)
// ---------------------------------------------------------------------------
template <bool C_F32, int BM, bool WRITE_VT>
__global__ __launch_bounds__(256) void gemm_bt(
    const unsigned short* __restrict__ A,
    const unsigned short* __restrict__ Bt,
    void* __restrict__ Cv, unsigned short* __restrict__ vt,
    int M, int N, int K)
{
    __shared__ __align__(16) unsigned short As[BM * 32];
    __shared__ __align__(16) unsigned short Bs[128 * 32];
    const int t = threadIdx.x, lane = t & 63, w = t >> 6;
    const int quad = lane >> 4, ln = lane & 15;
    const int bm = blockIdx.x, bn = blockIdx.y;
    constexpr int NI = (BM == 128) ? 4 : 2;
    const int mw = (BM == 128) ? (w & 1) * 64 : 0;
    const int nw = (BM == 128) ? (w >> 1) * 64 : w * 32;
    float4_ acc[4][NI] = {};

    constexpr int AROWS = BM / 4;      // rows of A staged per wave
    const unsigned short* Ag = A  + (size_t)(bm * BM + w * AROWS + (lane >> 2)) * K + (lane & 3) * 8;
    const unsigned short* Bg = Bt + (size_t)(bn * 128 + w * 32 + (lane >> 2)) * K + (lane & 3) * 8;
    unsigned short* lA = &As[(w * AROWS) * 32 + lane * 8];
    unsigned short* lB = &Bs[(w * 32) * 32 + lane * 8];

    for (int k0 = 0; k0 < K; k0 += 32) {
        g2l16(Ag + k0, lA);
        if (BM == 128) g2l16(Ag + (size_t)16 * K + k0, lA + 16 * 32);
        g2l16(Bg + k0,                  lB);
        g2l16(Bg + (size_t)16 * K + k0, lB + 16 * 32);
        __syncthreads();
        short8 a[4], b[NI];
        #pragma unroll
        for (int i = 0; i < 4; ++i)
            a[i] = *(const short8*)(&As[(mw + i * 16 + ln) * 32 + quad * 8]);
        #pragma unroll
        for (int i = 0; i < NI; ++i)
            b[i] = *(const short8*)(&Bs[(nw + i * 16 + ln) * 32 + quad * 8]);
        #pragma unroll
        for (int mi = 0; mi < 4; ++mi)
            #pragma unroll
            for (int ni = 0; ni < NI; ++ni)
                acc[mi][ni] = __builtin_amdgcn_mfma_f32_16x16x32_bf16(
                    a[mi], b[ni], acc[mi][ni], 0, 0, 0);
        __syncthreads();
    }

    const int row0 = bm * BM + mw + quad * 4;
    const int col0 = bn * 128 + nw + ln;
    #pragma unroll
    for (int mi = 0; mi < 4; ++mi)
        #pragma unroll
        for (int ni = 0; ni < NI; ++ni) {
            #pragma unroll
            for (int i = 0; i < 4; ++i) {
                size_t idx = (size_t)(row0 + mi * 16 + i) * N + col0 + ni * 16;
                if (C_F32) ((float*)Cv)[idx] = acc[mi][ni][i];
                else       ((unsigned short*)Cv)[idx] = f2bf(acc[mi][ni][i]);
            }
            if (WRITE_VT && col0 + ni * 16 >= 2 * C_) {
                int d     = col0 + ni * 16 - 2 * C_;       // 0..1023
                int token = row0 + mi * 16;                // 4-aligned, +i
                int b     = token >> 11, tloc = token & 2047;
                union { fp16x2 h2[2]; ushort4_ u4; } pk;
                pk.h2[0] = __builtin_amdgcn_cvt_pkrtz(acc[mi][ni][0], acc[mi][ni][1]);
                pk.h2[1] = __builtin_amdgcn_cvt_pkrtz(acc[mi][ni][2], acc[mi][ni][3]);
                *(ushort4_*)(vt + ((size_t)b * 1024 + d) * T_ + tloc) = pk.u4;
            }
        }
}

// ---------------------------------------------------------------------------
// attn per-K-tile compute: QK^T (bf16 K=32 MFMA, swapped operands) ->
// in-register exp2 softmax numerator -> PV (f16 K=16 MFMA, P stays in regs).
// Ksb: bf16 [kk][d] (64x72). Vsb: f16 [d][kk] (64x72), XOR-8B swizzled.
// ---------------------------------------------------------------------------
__device__ __forceinline__ void attn_tile(
    const unsigned short (*Ksb)[72], const unsigned short (*Vsb)[72],
    const short8 (&qf)[2][2], float4_ (&ot)[4][2], float (&ls)[2],
    int quad, int ln)
{
    const float C1 = 0.125f * 1.44269504f;   // scale * log2(e)
    const float C2 = 8.0f * 1.44269504f;     // fixed shift * log2(e)
    half4_ pf[4][2];
    #pragma unroll
    for (int ct = 0; ct < 4; ++ct) {
        short8 kb0 = *(const short8*)(&Ksb[ct * 16 + ln][quad * 8]);
        short8 kb1 = *(const short8*)(&Ksb[ct * 16 + ln][32 + quad * 8]);
        #pragma unroll
        for (int qm = 0; qm < 2; ++qm) {
            float4_ st = {};
            st = __builtin_amdgcn_mfma_f32_16x16x32_bf16(kb0, qf[qm][0], st, 0, 0, 0);
            st = __builtin_amdgcn_mfma_f32_16x16x32_bf16(kb1, qf[qm][1], st, 0, 0, 0);
            float p0 = __builtin_amdgcn_exp2f(st[0] * C1 - C2);
            float p1 = __builtin_amdgcn_exp2f(st[1] * C1 - C2);
            float p2 = __builtin_amdgcn_exp2f(st[2] * C1 - C2);
            float p3 = __builtin_amdgcn_exp2f(st[3] * C1 - C2);
            ls[qm] += (p0 + p1) + (p2 + p3);
            union { fp16x2 h2[2]; half4_ h4; } u;
            u.h2[0] = __builtin_amdgcn_cvt_pkrtz(p0, p1);
            u.h2[1] = __builtin_amdgcn_cvt_pkrtz(p2, p3);
            pf[ct][qm] = u.h4;
        }
    }
    // Ot += V^T P^T : A-frag = Vs[d=dt*16+ln][kk=ct*16+quad*4 ..+3]
    const char* vbase = (const char*)(&Vsb[0][0]);
    const int rsw = ln & 8;            // read-side addr XOR (row&8 == ln&8)
    #pragma unroll
    for (int dt = 0; dt < 4; ++dt) {
        int roff = (dt * 16 + ln) * 144;
        #pragma unroll
        for (int ct = 0; ct < 4; ++ct) {
            half4_ va = *(const half4_*)(vbase + roff + ((ct * 32 + quad * 8) ^ rsw));
            #pragma unroll
            for (int qm = 0; qm < 2; ++qm)
                ot[dt][qm] = __builtin_amdgcn_mfma_f32_16x16x16f16(
                    va, pf[ct][qm], ot[dt][qm], 0, 0, 0);
        }
    }
}

// ---------------------------------------------------------------------------
// Flash attention, W=32: 256 threads = 4 waves, 128-row Q-tile, wave w owns
// q-rows w*32..+31 as 2 subtiles (qm). KT=64, 32 K-tiles.
// R4: K/V LDS DOUBLE-BUFFER -> ONE barrier per K-tile (was 2). Iter i
// writes buf[i^1] from regs prefetched a full iteration earlier (vmcnt
// landed) while computing buf[i]; the single end-of-body barrier covers
// both hazards. Unrolled x2 with named regA/regB (static reg indexing).
// Diagnosis trail: R1/R2 8-wave restructures regressed (70->86/94);
// R3 proved bank conflicts off the critical path (6.3M->2.1M, time flat)
// -> remaining theory: barrier-drain serialization, attacked here.
// Vs swizzle kept (verified conflict cut, zero cost): byte-addr ^= row&8,
// write-side register half-swap + read-side addr XOR.
// ---------------------------------------------------------------------------
__global__ __launch_bounds__(256) void attn(
    const unsigned short* __restrict__ qkv,
    const unsigned short* __restrict__ vt,
    unsigned short* __restrict__ Y)
{
    __shared__ __align__(16) unsigned short Qs[128][72];     // bf16 [q][d]
    __shared__ __align__(16) unsigned short Ks[2][64][72];   // bf16 [kk][d]
    __shared__ __align__(16) unsigned short Vs[2][64][72];   // f16  [d][kk], swizzled

    const int t = threadIdx.x;
    const int qt = blockIdx.x, bh = blockIdx.y;
    const int b = bh >> 4, h = bh & 15;
    const int lane = t & 63, w = t >> 6;
    const int quad = lane >> 4, ln = lane & 15;

    const unsigned short* Qg  = qkv + (size_t)b * T_ * (3 * C_) + (size_t)h * HD_;
    const unsigned short* Kg  = Qg + C_;
    const unsigned short* Vtg = vt + (size_t)bh * HD_ * T_;

    // stage Q tile (128x64): 1024 chunks, 4/thread
    #pragma unroll
    for (int cc = 0; cc < 4; ++cc) {
        int c = cc * 256 + t;
        int r = c >> 3, col = (c & 7) * 8;
        *(uint4*)(&Qs[r][col]) = *(const uint4*)(Qg + (size_t)(qt * 128 + r) * (3 * C_) + col);
    }

    // K/V staging coords: thread t -> rows r0/r1, col c0v (16B each)
    const int r0 = t >> 3, c0v = (t & 7) * 8;
    const int r1 = r0 + 32;
    const int vsw = r0 & 8;            // write-side half-swap flag (r1&8 == r0&8)

    // tile loader / storer (regs <-> global / LDS)
    auto load_kv = [&](uint4& k0, uint4& k1, uint4& v0, uint4& v1, int kb) {
        k0 = *(const uint4*)(Kg + (size_t)(kb + r0) * (3 * C_) + c0v);
        k1 = *(const uint4*)(Kg + (size_t)(kb + r1) * (3 * C_) + c0v);
        v0 = *(const uint4*)(Vtg + (size_t)r0 * T_ + kb + c0v);
        v1 = *(const uint4*)(Vtg + (size_t)r1 * T_ + kb + c0v);
    };
    auto store_kv = [&](unsigned short (*Kb)[72], unsigned short (*Vb)[72],
                        uint4 k0, uint4 k1, uint4 v0, uint4 v1) {
        *(uint4*)(&Kb[r0][c0v]) = k0;
        *(uint4*)(&Kb[r1][c0v]) = k1;
        if (vsw) {
            uint4 s;
            s.x = v0.z; s.y = v0.w; s.z = v0.x; s.w = v0.y; v0 = s;
            s.x = v1.z; s.y = v1.w; s.z = v1.x; s.w = v1.y; v1 = s;
        }
        *(uint4*)(&Vb[r0][c0v]) = v0;
        *(uint4*)(&Vb[r1][c0v]) = v1;
    };

    // prefetch tile 0 into regA
    uint4 ka0, ka1, va0, va1, kb0r, kb1r, vb0r, vb1r;
    load_kv(ka0, ka1, va0, va1, 0);

    __syncthreads();                   // Q staged

    // hoisted Q frags: B-operand, lane holds Q[q=w*32+qm*16+ln][d=dh*32+quad*8..+7]
    short8 qf[2][2];
    #pragma unroll
    for (int qm = 0; qm < 2; ++qm)
        #pragma unroll
        for (int dh = 0; dh < 2; ++dh)
            qf[qm][dh] = *(const short8*)(&Qs[w * 32 + qm * 16 + ln][dh * 32 + quad * 8]);

    // tile0 -> buf0, prefetch tile1 -> regB
    store_kv(Ks[0], Vs[0], ka0, ka1, va0, va1);
    load_kv(kb0r, kb1r, vb0r, vb1r, 64);
    __syncthreads();                   // buf0 ready

    float4_ ot[4][2] = {};             // [dt][qm]: Ot[d=dt*16+quad*4+i][q=qm*16+ln]
    float ls[2] = {0.f, 0.f};

    constexpr int NT = T_ / 64;        // 32 K-tiles
    for (int it = 0; it < NT; it += 2) {
        // phase A: compute buf0 (tile it); write regB (tile it+1) -> buf1;
        // issue tile it+2 -> regA
        if (it + 1 < NT) store_kv(Ks[1], Vs[1], kb0r, kb1r, vb0r, vb1r);
        if (it + 2 < NT) load_kv(ka0, ka1, va0, va1, (it + 2) * 64);
        attn_tile(Ks[0], Vs[0], qf, ot, ls, quad, ln);
        __syncthreads();

        // phase B: compute buf1 (tile it+1); write regA (tile it+2) -> buf0;
        // issue tile it+3 -> regB
        if (it + 2 < NT) store_kv(Ks[0], Vs[0], ka0, ka1, va0, va1);
        if (it + 3 < NT) load_kv(kb0r, kb1r, vb0r, vb1r, (it + 3) * 64);
        if (it + 1 < NT) attn_tile(Ks[1], Vs[1], qf, ot, ls, quad, ln);
        __syncthreads();
    }

    // reduce ls across the 4 quads (lane bits 4,5)
    #pragma unroll
    for (int qm = 0; qm < 2; ++qm) {
        ls[qm] += __shfl_xor(ls[qm], 16, 64);
        ls[qm] += __shfl_xor(ls[qm], 32, 64);
    }

    // epilogue: Y[b, q, h*64 + d]; q = qt*128 + w*32 + qm*16 + ln
    #pragma unroll
    for (int qm = 0; qm < 2; ++qm) {
        unsigned short* Yr = Y + ((size_t)b * T_ + qt * 128 + w * 32 + qm * 16 + ln) * C_ + h * HD_;
        float inv = 1.0f / ls[qm];
        #pragma unroll
        for (int dt = 0; dt < 4; ++dt)
            #pragma unroll
            for (int i = 0; i < 4; ++i)
                Yr[dt * 16 + quad * 4 + i] = f2bf(ot[dt][qm][i] * inv);
    }
}

extern "C" void kernel_launch(void* const* d_in, const int* in_sizes, int n_in,
                              void* d_out, int out_size, void* d_ws, size_t ws_size,
                              hipStream_t stream)
{
    const float* x      = (const float*)d_in[0];   // [4096,1024]
    const float* w_attn = (const float*)d_in[1];   // [1024,3072]
    const float* w_proj = (const float*)d_in[2];   // [1024,1024]
    float* out = (float*)d_out;                    // [4096,1024]

    // ws (2B elems): qkv 12.58M | y/xb 4.19M | wTa 3.15M | wTp 1.05M | vt 4.19M
    unsigned short* qkv = (unsigned short*)d_ws;
    unsigned short* y   = qkv + (size_t)4096 * 3072;   // also xb (dead after gemm1)
    unsigned short* wTa = y   + (size_t)4096 * 1024;
    unsigned short* wTp = wTa + (size_t)3072 * 1024;
    unsigned short* vt  = wTp + (size_t)1024 * 1024;   // f16
    unsigned short* xb  = y;

    prep<<<2048 + 16 * 48 + 16 * 16, 256, 0, stream>>>(x, xb, w_attn, wTa, w_proj, wTp);

    gemm_bt<false, 128, true><<<dim3(32, 24), 256, 0, stream>>>(
        xb, wTa, qkv, vt, 4096, 3072, 1024);
    attn<<<dim3(16, 32), 256, 0, stream>>>(qkv, vt, y);
    gemm_bt<true, 64, false><<<dim3(64, 8), 256, 0, stream>>>(
        y, wTp, out, nullptr, 4096, 1024, 1024);
}